// Round 3
// baseline (494.147 us; speedup 1.0000x reference)
//
#include <hip/hip_runtime.h>

// Problem constants (B=4, L=4096, E=512, H=16, D=32)
#define EMBED  512
#define NHEAD  16
#define HDIM   32
#define NBATCH 4
#define SEQ    4096
#define NROWS  (NBATCH * SEQ)   // 16384
#define FEPS   1e-6f

typedef __attribute__((ext_vector_type(8))) short short8;
typedef __attribute__((ext_vector_type(4))) float f32x4;

// ---- bf16 split helpers (RNE) ----
__device__ __forceinline__ short f2bf(float x) {
    unsigned u = __float_as_uint(x);
    u += 0x7FFFu + ((u >> 16) & 1u);
    return (short)(u >> 16);
}
__device__ __forceinline__ float bf2f(short h) {
    return __uint_as_float(((unsigned)(unsigned short)h) << 16);
}

// ---- all 4 weights split in one launch: seg = blockIdx.x>>8 ----
__global__ __launch_bounds__(256)
void convert_w4(const float* __restrict__ W0, const float* __restrict__ W1,
                const float* __restrict__ W2, const float* __restrict__ W3,
                short* __restrict__ H0, short* __restrict__ L0,
                short* __restrict__ H1, short* __restrict__ L1,
                short* __restrict__ H2, short* __restrict__ L2,
                short* __restrict__ H3, short* __restrict__ L3) {
    const int seg = blockIdx.x >> 8;
    const int i = ((blockIdx.x & 255) * 256 + threadIdx.x) * 4;
    const float* W = (seg == 0) ? W0 : (seg == 1) ? W1 : (seg == 2) ? W2 : W3;
    short* H = (seg == 0) ? H0 : (seg == 1) ? H1 : (seg == 2) ? H2 : H3;
    short* L = (seg == 0) ? L0 : (seg == 1) ? L1 : (seg == 2) ? L2 : L3;
    float4 v = *(const float4*)(W + i);
    short4 h, l;
    h.x = f2bf(v.x); l.x = f2bf(v.x - bf2f(h.x));
    h.y = f2bf(v.y); l.y = f2bf(v.y - bf2f(h.y));
    h.z = f2bf(v.z); l.z = f2bf(v.z - bf2f(h.z));
    h.w = f2bf(v.w); l.w = f2bf(v.w - bf2f(h.w));
    *(short4*)(H + i) = h;
    *(short4*)(L + i) = l;
}

// ---- split-bf16 MFMA GEMM: C[m,n] = sum_k A[m,k] * W[n,k] ----
// 128M x 64N tile, 1024 blocks (4/CU grid), 256 threads = 4 waves (32 rows
// each, full 64-col width). Register prefetch of next A-chunk + B-frags.
// Epilogue staged through LDS -> 256-B contiguous dwordx4 stores (no RFO).
// Block swizzle: y-major so n-blocks sharing an A-strip land on one XCD.
#define LDA 40   // padded LDS row (shorts)

template <int EPI>
__global__ __launch_bounds__(256, 3)
void gemm_mfma(const float* __restrict__ A, const short* __restrict__ Whi,
               const short* __restrict__ Wlo, float* __restrict__ C) {
    __shared__ char smem[34048];                 // 20480 staging / 33792 epilogue
    short (*Ah)[LDA] = (short (*)[LDA])smem;
    short (*Al)[LDA] = (short (*)[LDA])(smem + 10240);

    const int tid  = threadIdx.x;
    const int lane = tid & 63;
    const int wave = tid >> 6;
    const int wm   = wave * 32;
    const int l15  = lane & 15;
    const int kg   = lane >> 4;

    const int lin = blockIdx.x;                  // 0..1023, y-major swizzle
    const int bn  = (lin >> 7) * 64;             // x strides by 128 blocks
    const int bm  = (lin & 127) * 128;

    const int sr = tid >> 1;                     // staging row 0..127
    const int sk = (tid & 1) * 16;               // staging k-offset 0/16
    const float* Ap = A + (size_t)(bm + sr) * EMBED + sk;

    const short* Bh = Whi + (size_t)(bn + l15) * EMBED + kg * 8;
    const short* Bl = Wlo + (size_t)(bn + l15) * EMBED + kg * 8;

    f32x4 acc[2][4];
#pragma unroll
    for (int i = 0; i < 2; ++i)
#pragma unroll
        for (int j = 0; j < 4; ++j) acc[i][j] = (f32x4)0.0f;

    float4 a[4];
    short8 bh[4], bl[4], bhn[4], bln[4];
#pragma unroll
    for (int p = 0; p < 4; ++p) a[p] = *(const float4*)(Ap + p * 4);
#pragma unroll
    for (int j = 0; j < 4; ++j) {
        bh[j] = *(const short8*)(Bh + (size_t)j * 16 * EMBED);
        bl[j] = *(const short8*)(Bl + (size_t)j * 16 * EMBED);
    }

#pragma unroll 1
    for (int k0 = 0; k0 < EMBED; k0 += 32) {
        __syncthreads();                         // prior LDS reads complete
        {
            float v[16] = {a[0].x, a[0].y, a[0].z, a[0].w,
                           a[1].x, a[1].y, a[1].z, a[1].w,
                           a[2].x, a[2].y, a[2].z, a[2].w,
                           a[3].x, a[3].y, a[3].z, a[3].w};
            short8 hv0, lv0, hv1, lv1;
#pragma unroll
            for (int q = 0; q < 8; ++q) {
                short hb = f2bf(v[q]);
                hv0[q] = hb; lv0[q] = f2bf(v[q] - bf2f(hb));
            }
#pragma unroll
            for (int q = 0; q < 8; ++q) {
                short hb = f2bf(v[8 + q]);
                hv1[q] = hb; lv1[q] = f2bf(v[8 + q] - bf2f(hb));
            }
            *(short8*)&Ah[sr][sk]     = hv0;
            *(short8*)&Ah[sr][sk + 8] = hv1;
            *(short8*)&Al[sr][sk]     = lv0;
            *(short8*)&Al[sr][sk + 8] = lv1;
        }
        __syncthreads();

        if (k0 + 32 < EMBED) {                   // prefetch next chunk
#pragma unroll
            for (int p = 0; p < 4; ++p)
                a[p] = *(const float4*)(Ap + k0 + 32 + p * 4);
#pragma unroll
            for (int j = 0; j < 4; ++j) {
                bhn[j] = *(const short8*)(Bh + (size_t)j * 16 * EMBED + k0 + 32);
                bln[j] = *(const short8*)(Bl + (size_t)j * 16 * EMBED + k0 + 32);
            }
        }

        short8 ah[2], alr[2];
#pragma unroll
        for (int i = 0; i < 2; ++i) {
            ah[i]  = *(const short8*)&Ah[wm + i * 16 + l15][kg * 8];
            alr[i] = *(const short8*)&Al[wm + i * 16 + l15][kg * 8];
        }
#pragma unroll
        for (int i = 0; i < 2; ++i)
#pragma unroll
            for (int j = 0; j < 4; ++j) {
                acc[i][j] = __builtin_amdgcn_mfma_f32_16x16x32_bf16(ah[i],  bh[j], acc[i][j], 0, 0, 0);
                acc[i][j] = __builtin_amdgcn_mfma_f32_16x16x32_bf16(ah[i],  bl[j], acc[i][j], 0, 0, 0);
                acc[i][j] = __builtin_amdgcn_mfma_f32_16x16x32_bf16(alr[i], bh[j], acc[i][j], 0, 0, 0);
            }
#pragma unroll
        for (int j = 0; j < 4; ++j) { bh[j] = bhn[j]; bl[j] = bln[j]; }
    }

    // ---- epilogue: LDS transpose -> full-line contiguous stores ----
    __syncthreads();                             // staging reads all done
    float* Cw = (float*)smem + wave * 2112;      // 32 rows x 66 (pad) floats
#pragma unroll
    for (int i = 0; i < 2; ++i)
#pragma unroll
        for (int j = 0; j < 4; ++j)
#pragma unroll
            for (int r = 0; r < 4; ++r) {
                float vv = acc[i][j][r];
                if (EPI == 1) vv = (vv > 0.f) ? (vv + 1.f) : __expf(vv);
                else if (EPI == 2) vv = vv * (1.0f / (float)SEQ);
                Cw[(i * 16 + kg * 4 + r) * 66 + j * 16 + l15] = vv;
            }
    // same-wave LDS RAW: compiler inserts lgkmcnt wait
#pragma unroll
    for (int inst = 0; inst < 8; ++inst) {
        f32x4 cv = *(const f32x4*)&Cw[(inst * 4 + kg) * 66 + l15 * 4];
        const int row = bm + wm + inst * 4 + kg;
        *(float4*)(C + (size_t)row * EMBED + bn + l15 * 4) = *(float4*)&cv;
    }
}

// ---- KV + Ksum via split-bf16 MFMA -------------------------------------
// KV[b,h] = K^T @ V (32x32, K-dim = s). Ksum via extra MFMA with B = ones.
// grid (16 s-chunks, 64 bh); block = 256 s rows in 2 macro-iters of 128.
__global__ __launch_bounds__(256)
void kv_ksum_mfma(const float* __restrict__ Kf, const float* __restrict__ Vf,
                  float* __restrict__ KV, float* __restrict__ Ksum) {
    __shared__ char smem[34816];
    short (*Kh)[34] = (short (*)[34])smem;
    short (*Kl)[34] = (short (*)[34])(smem + 8704);
    short (*Vh)[34] = (short (*)[34])(smem + 17408);
    short (*Vl)[34] = (short (*)[34])(smem + 26112);

    const int bh_ = blockIdx.y;
    const int b = bh_ >> 4, h = bh_ & 15;
    const int s0 = blockIdx.x * 256;
    const int t = threadIdx.x;
    const int lane = t & 63, wave = t >> 6;
    const int l15 = lane & 15, kg = lane >> 4;
    const int ws = wave * 32;                    // wave's s-window in tile

    const int sl = t >> 1;                       // staging row 0..127
    const int dsel = (t & 1) * 16;
    const float* Kbase = Kf + (size_t)b * SEQ * EMBED + h * HDIM;
    const float* Vbase = Vf + (size_t)b * SEQ * EMBED + h * HDIM;

    f32x4 kvacc[2][2], ksacc[2];
#pragma unroll
    for (int i = 0; i < 2; ++i) {
        ksacc[i] = (f32x4)0.0f;
#pragma unroll
        for (int j = 0; j < 2; ++j) kvacc[i][j] = (f32x4)0.0f;
    }
    short8 ones;
#pragma unroll
    for (int q = 0; q < 8; ++q) ones[q] = (short)0x3F80;   // bf16 1.0

    float4 kx[4], vx[4];
#pragma unroll
    for (int p = 0; p < 4; ++p) {
        kx[p] = *(const float4*)(Kbase + (size_t)(s0 + sl) * EMBED + dsel + 4 * p);
        vx[p] = *(const float4*)(Vbase + (size_t)(s0 + sl) * EMBED + dsel + 4 * p);
    }

#pragma unroll 1
    for (int it = 0; it < 2; ++it) {
        __syncthreads();
        {
            float kv_[8] = {kx[0].x, kx[0].y, kx[0].z, kx[0].w, kx[1].x, kx[1].y, kx[1].z, kx[1].w};
            float kv2[8] = {kx[2].x, kx[2].y, kx[2].z, kx[2].w, kx[3].x, kx[3].y, kx[3].z, kx[3].w};
            float vv_[8] = {vx[0].x, vx[0].y, vx[0].z, vx[0].w, vx[1].x, vx[1].y, vx[1].z, vx[1].w};
            float vv2[8] = {vx[2].x, vx[2].y, vx[2].z, vx[2].w, vx[3].x, vx[3].y, vx[3].z, vx[3].w};
            short8 h0, l0, h1, l1;
#pragma unroll
            for (int q = 0; q < 8; ++q) { short hb = f2bf(kv_[q]); h0[q] = hb; l0[q] = f2bf(kv_[q] - bf2f(hb)); }
#pragma unroll
            for (int q = 0; q < 8; ++q) { short hb = f2bf(kv2[q]); h1[q] = hb; l1[q] = f2bf(kv2[q] - bf2f(hb)); }
            *(short8*)&Kh[sl][dsel] = h0; *(short8*)&Kh[sl][dsel + 8] = h1;
            *(short8*)&Kl[sl][dsel] = l0; *(short8*)&Kl[sl][dsel + 8] = l1;
#pragma unroll
            for (int q = 0; q < 8; ++q) { short hb = f2bf(vv_[q]); h0[q] = hb; l0[q] = f2bf(vv_[q] - bf2f(hb)); }
#pragma unroll
            for (int q = 0; q < 8; ++q) { short hb = f2bf(vv2[q]); h1[q] = hb; l1[q] = f2bf(vv2[q] - bf2f(hb)); }
            *(short8*)&Vh[sl][dsel] = h0; *(short8*)&Vh[sl][dsel + 8] = h1;
            *(short8*)&Vl[sl][dsel] = l0; *(short8*)&Vl[sl][dsel + 8] = l1;
        }
        __syncthreads();
        if (it == 0) {
#pragma unroll
            for (int p = 0; p < 4; ++p) {
                kx[p] = *(const float4*)(Kbase + (size_t)(s0 + 128 + sl) * EMBED + dsel + 4 * p);
                vx[p] = *(const float4*)(Vbase + (size_t)(s0 + 128 + sl) * EMBED + dsel + 4 * p);
            }
        }
        // per-lane gathers: A[m=d][k=s], B[n=e][k=s]; conflict-free banks
        short8 kah[2], kal[2], vbh[2], vbl[2];
#pragma unroll
        for (int i = 0; i < 2; ++i) {
#pragma unroll
            for (int q = 0; q < 8; ++q) {
                const int srow = ws + kg * 8 + q;
                const int col  = i * 16 + l15;
                kah[i][q] = Kh[srow][col];
                kal[i][q] = Kl[srow][col];
                vbh[i][q] = Vh[srow][col];
                vbl[i][q] = Vl[srow][col];
            }
        }
#pragma unroll
        for (int i = 0; i < 2; ++i) {
#pragma unroll
            for (int j = 0; j < 2; ++j) {
                kvacc[i][j] = __builtin_amdgcn_mfma_f32_16x16x32_bf16(kah[i], vbh[j], kvacc[i][j], 0, 0, 0);
                kvacc[i][j] = __builtin_amdgcn_mfma_f32_16x16x32_bf16(kah[i], vbl[j], kvacc[i][j], 0, 0, 0);
                kvacc[i][j] = __builtin_amdgcn_mfma_f32_16x16x32_bf16(kal[i], vbh[j], kvacc[i][j], 0, 0, 0);
            }
            ksacc[i] = __builtin_amdgcn_mfma_f32_16x16x32_bf16(kah[i], ones, ksacc[i], 0, 0, 0);
            ksacc[i] = __builtin_amdgcn_mfma_f32_16x16x32_bf16(kal[i], ones, ksacc[i], 0, 0, 0);
        }
    }

    // ---- cross-wave reduce in LDS, then one atomic per element ----
    __syncthreads();
    float* red = (float*)smem;                   // 4 x 1056 floats
    float* myred = red + wave * 1056;
#pragma unroll
    for (int i = 0; i < 2; ++i)
#pragma unroll
        for (int j = 0; j < 2; ++j)
#pragma unroll
            for (int r = 0; r < 4; ++r)
                myred[(i * 16 + kg * 4 + r) * 32 + j * 16 + l15] = kvacc[i][j][r];
    if (l15 == 0) {
#pragma unroll
        for (int i = 0; i < 2; ++i)
#pragma unroll
            for (int r = 0; r < 4; ++r)
                myred[1024 + i * 16 + kg * 4 + r] = ksacc[i][r];
    }
    __syncthreads();
    float* kvout = KV + (size_t)bh_ * 1024;
    for (int idx = t; idx < 1024; idx += 256) {
        float s4 = red[idx] + red[1056 + idx] + red[2112 + idx] + red[3168 + idx];
        atomicAdd(&kvout[idx], s4);
    }
    if (t < 32) {
        float s4 = red[1024 + t] + red[1056 + 1024 + t] + red[2112 + 1024 + t] + red[3168 + 1024 + t];
        atomicAdd(&Ksum[bh_ * 32 + t], s4);
    }
}

// ---- message (in place): Q[l,h,:] <- (SEQ/(Q.Ksum+eps)) * Q @ KV[b,h] ----
__global__ __launch_bounds__(512)
void message_kernel(float* __restrict__ Q, const float* __restrict__ KV,
                    const float* __restrict__ Ksum) {
    const int blk  = blockIdx.x;
    const int row0 = blk * 4;
    const int b    = row0 >> 12;
    const int t    = threadIdx.x;
    const int h    = t >> 5, e = t & 31;

    __shared__ float q[4][EMBED];
    __shared__ float ks[EMBED];
    ks[t] = Ksum[b * EMBED + t];
#pragma unroll
    for (int r = 0; r < 4; ++r) q[r][t] = Q[(size_t)(row0 + r) * EMBED + t];

    const float* kvh = KV + (size_t)(b * NHEAD + h) * HDIM * HDIM + e;
    float kc[HDIM];
#pragma unroll
    for (int d = 0; d < HDIM; ++d) kc[d] = kvh[d * HDIM];
    __syncthreads();

#pragma unroll
    for (int r = 0; r < 4; ++r) {
        float zden = FEPS, m = 0.f;
#pragma unroll
        for (int d = 0; d < HDIM; ++d) {
            float qd = q[r][h * HDIM + d];
            zden = fmaf(qd, ks[h * HDIM + d], zden);
            m    = fmaf(qd, kc[d], m);
        }
        Q[(size_t)(row0 + r) * EMBED + t] = m * ((float)SEQ / zden);
    }
}

// ---- launch ----
extern "C" void kernel_launch(void* const* d_in, const int* in_sizes, int n_in,
                              void* d_out, int out_size, void* d_ws, size_t ws_size,
                              hipStream_t stream) {
    const float* query = (const float*)d_in[0];
    const float* key   = (const float*)d_in[1];
    const float* value = (const float*)d_in[2];
    const float* Wq    = (const float*)d_in[3];
    const float* Wk    = (const float*)d_in[4];
    const float* Wv    = (const float*)d_in[5];
    const float* Wm    = (const float*)d_in[6];
    float* out = (float*)d_out;

    float* ws  = (float*)d_ws;
    float* Qb  = ws;                              // 16384*512 fp32
    float* Kb  = Qb + (size_t)NROWS * EMBED;
    float* Vb  = Kb + (size_t)NROWS * EMBED;
    float* KVb = Vb + (size_t)NROWS * EMBED;      // 64*32*32
    float* KSb = KVb + 64 * HDIM * HDIM;          // 64*32
    short* wsp = (short*)(KSb + 64 * HDIM);
    const int WN = EMBED * EMBED;
    short* WqH = wsp;            short* WqL = wsp + WN;
    short* WkH = wsp + 2 * WN;   short* WkL = wsp + 3 * WN;
    short* WvH = wsp + 4 * WN;   short* WvL = wsp + 5 * WN;
    short* WmH = wsp + 6 * WN;   short* WmL = wsp + 7 * WN;

    hipMemsetAsync(KVb, 0, (64 * HDIM * HDIM + 64 * HDIM) * sizeof(float), stream);

    convert_w4<<<1024, 256, 0, stream>>>(Wq, Wk, Wv, Wm,
                                         WqH, WqL, WkH, WkL,
                                         WvH, WvL, WmH, WmL);

    gemm_mfma<1><<<1024, 256, 0, stream>>>(query, WqH, WqL, Qb);
    gemm_mfma<1><<<1024, 256, 0, stream>>>(key,   WkH, WkL, Kb);
    gemm_mfma<2><<<1024, 256, 0, stream>>>(value, WvH, WvL, Vb);

    kv_ksum_mfma<<<dim3(16, 64), 256, 0, stream>>>(Kb, Vb, KVb, KSb);
    message_kernel<<<NROWS / 4, 512, 0, stream>>>(Qb, KVb, KSb);

    gemm_mfma<0><<<1024, 256, 0, stream>>>(Qb, WmH, WmL, out);
}